// Round 4
// baseline (540.623 us; speedup 1.0000x reference)
//
#include <hip/hip_runtime.h>
#include <hip/hip_bf16.h>
#include <stdint.h>

#define B_  4096
#define D_  1024
#define NS_ 16000
#define C_  1000
#define H_  256

typedef __attribute__((ext_vector_type(8))) short bf16x8;
typedef __attribute__((ext_vector_type(4))) float f32x4;

__device__ __forceinline__ unsigned short f2bf(float f) {
  union { float f; unsigned u; } v; v.f = f;
  unsigned u = v.u;
  u += 0x7FFF + ((u >> 16) & 1);   // round-to-nearest-even
  return (unsigned short)(u >> 16);
}

// ---------------- fp32 -> bf16 convert; keys rows permuted by posmap ----------------
__global__ void convert_kernel(const float4* __restrict__ q, const float4* __restrict__ keys,
                               const float4* __restrict__ fc1, const int* __restrict__ posmap,
                               ushort4* __restrict__ qb, ushort4* __restrict__ keysb,
                               ushort4* __restrict__ fc1b) {
  const size_t nq = (size_t)B_ * D_ / 4;
  const size_t nk = (size_t)NS_ * D_ / 4;
  const size_t nf = (size_t)H_ * D_ / 4;
  const size_t total = nq + nk + nf;
  for (size_t i = blockIdx.x * (size_t)blockDim.x + threadIdx.x; i < total;
       i += (size_t)gridDim.x * blockDim.x) {
    if (i < nq) {
      float4 v = q[i];
      ushort4 r; r.x = f2bf(v.x); r.y = f2bf(v.y); r.z = f2bf(v.z); r.w = f2bf(v.w);
      qb[i] = r;
    } else if (i < nq + nk) {
      size_t o = i - nq;
      size_t row = o >> 8;           // D_/4 = 256 float4 per row
      size_t c4  = o & 255;
      float4 v = keys[o];
      ushort4 r; r.x = f2bf(v.x); r.y = f2bf(v.y); r.z = f2bf(v.z); r.w = f2bf(v.w);
      keysb[(size_t)posmap[row] * 256 + c4] = r;
    } else {
      size_t o = i - nq - nk;
      float4 v = fc1[o];
      ushort4 r; r.x = f2bf(v.x); r.y = f2bf(v.y); r.z = f2bf(v.z); r.w = f2bf(v.w);
      fc1b[o] = r;
    }
  }
}

// ---------------- labels from one-hot + histogram (wave per support row) ------------
__global__ void labels_kernel(const float* __restrict__ values, int* __restrict__ labels,
                              int* __restrict__ hist) {
  const int s = (int)((blockIdx.x * blockDim.x + threadIdx.x) >> 6);
  const int lane = threadIdx.x & 63;
  if (s >= NS_) return;
  const float4* row = (const float4*)(values + (size_t)s * C_);
  int lab = -1;
  for (int j = lane; j < C_ / 4; j += 64) {
    float4 v = row[j];
    if (v.x > 0.5f) lab = j * 4 + 0;
    if (v.y > 0.5f) lab = j * 4 + 1;
    if (v.z > 0.5f) lab = j * 4 + 2;
    if (v.w > 0.5f) lab = j * 4 + 3;
    if (__ballot(lab >= 0)) break;     // one-hot: whole wave exits once found
  }
  if (lab >= 0) { labels[s] = lab; atomicAdd(&hist[lab], 1); }
}

// ---------------- exclusive prefix scan of hist -> boff[0..C_] (single block) -------
__global__ void scan_kernel(const int* __restrict__ hist, int* __restrict__ boff) {
  __shared__ int s[1024];
  const int t = threadIdx.x;
  int v = (t < C_) ? hist[t] : 0;
  s[t] = v; __syncthreads();
  for (int off = 1; off < 1024; off <<= 1) {
    int u = (t >= off) ? s[t - off] : 0;
    __syncthreads();
    s[t] += u;
    __syncthreads();
  }
  if (t == 0) boff[0] = 0;
  if (t < C_) boff[t + 1] = s[t];
}

// ---------------- scatter: sorted position for each support + sorted labels --------
__global__ void scatter_kernel(const int* __restrict__ labels, const int* __restrict__ boff,
                               int* __restrict__ cnt, int* __restrict__ posmap,
                               int* __restrict__ labsort) {
  const int sidx = blockIdx.x * blockDim.x + threadIdx.x;
  if (sidx >= NS_) return;
  const int lab = labels[sidx];
  const int pos = boff[lab] + atomicAdd(&cnt[lab], 1);
  posmap[sidx] = pos;
  labsort[pos] = lab;
}

// ---------------- 128x128 bf16 MFMA GEMM (A [M,K], B [N,K], both row-major) ---------
// MODE 0: fused epilogue -> aff = exp(beta[row]*acc); segmented run-sum over equal
//         sorted labels within each 16-col window (shfl Hillis-Steele); run heads
//         atomicAdd into outp[row*C_ + lab].
// MODE 1: x epilogue   -> outp[row*H_ + col] = relu(acc + bias[col])
// LDS k-chunk XOR swizzle: LDS[r][c] holds global 16B k-chunk (c ^ (r&7)).
template<int MODE>
__global__ __launch_bounds__(256, 2) void gemm_kernel(
    const short* __restrict__ A, const short* __restrict__ Bm,
    const float* __restrict__ beta, const float* __restrict__ bias,
    float* __restrict__ outp, const int* __restrict__ labsort)
{
  __shared__ short As[128 * 64];
  __shared__ short Bs[128 * 64];
  __shared__ float sbeta[128];
  __shared__ int   slab[144];          // 128 labels + pad (monotonic; pad = -1)

  const int tid  = threadIdx.x;
  const int wave = tid >> 6, lane = tid & 63;
  const int quad = lane >> 4, l16 = lane & 15;
  const int wm = wave >> 1, wn = wave & 1;     // 2x2 wave grid, 64x64 per wave
  const int rstart = blockIdx.x * 128;
  const int nstart = blockIdx.y * 128;

  if (MODE == 0) {
    if (tid < 128) { sbeta[tid] = beta[rstart + tid]; slab[tid] = labsort[nstart + tid]; }
    if (tid >= 128 && tid < 144) slab[tid] = -1;
  }

  f32x4 acc[4][4];
  #pragma unroll
  for (int i = 0; i < 4; ++i)
    #pragma unroll
    for (int j = 0; j < 4; ++j) acc[i][j] = (f32x4)0.f;

  const int r_  = (lane >> 3);             // 0..7 (row within 8-row chunk)
  const int kc_ = ((lane & 7) ^ r_) * 8;   // swizzled 16B k-chunk element offset

  for (int kt = 0; kt < D_; kt += 64) {
    __syncthreads();
    #pragma unroll
    for (int i = 0; i < 4; ++i) {
      const int chunk = i * 4 + wave;       // 0..15, wave-uniform
      const int r = chunk * 8 + r_;         // 0..127
      const short* gA = A  + (size_t)(rstart + r) * D_ + kt + kc_;
      const short* gB = Bm + (size_t)(nstart + r) * D_ + kt + kc_;
      __builtin_amdgcn_global_load_lds(
          (const __attribute__((address_space(1))) void*)gA,
          (__attribute__((address_space(3))) void*)(As + chunk * 512), 16, 0, 0);
      __builtin_amdgcn_global_load_lds(
          (const __attribute__((address_space(1))) void*)gB,
          (__attribute__((address_space(3))) void*)(Bs + chunk * 512), 16, 0, 0);
    }
    __syncthreads();
    #pragma unroll
    for (int ks = 0; ks < 64; ks += 32) {
      bf16x8 af[4], bfr[4];
      const int kb = (ks >> 3) + quad;      // global k-chunk index 0..7
      #pragma unroll
      for (int mt = 0; mt < 4; ++mt) {
        const int row = wm * 64 + mt * 16 + l16;
        af[mt] = *(const bf16x8*)(As + row * 64 + ((kb ^ (row & 7)) << 3));
      }
      #pragma unroll
      for (int nt = 0; nt < 4; ++nt) {
        const int row = wn * 64 + nt * 16 + l16;
        bfr[nt] = *(const bf16x8*)(Bs + row * 64 + ((kb ^ (row & 7)) << 3));
      }
      #pragma unroll
      for (int mt = 0; mt < 4; ++mt)
        #pragma unroll
        for (int nt = 0; nt < 4; ++nt)
          acc[mt][nt] = __builtin_amdgcn_mfma_f32_16x16x32_bf16(af[mt], bfr[nt], acc[mt][nt], 0, 0, 0);
    }
  }

  if (MODE == 0) {
    #pragma unroll
    for (int mt = 0; mt < 4; ++mt) {
      const int rbase = wm * 64 + mt * 16 + quad * 4;
      #pragma unroll
      for (int nt = 0; nt < 4; ++nt) {
        const int cloc = wn * 64 + nt * 16 + l16;
        const int lab = slab[cloc];
        float v0 = __expf(sbeta[rbase + 0] * acc[mt][nt][0]);
        float v1 = __expf(sbeta[rbase + 1] * acc[mt][nt][1]);
        float v2 = __expf(sbeta[rbase + 2] * acc[mt][nt][2]);
        float v3 = __expf(sbeta[rbase + 3] * acc[mt][nt][3]);
        // segmented run-sum across the 16-col window (labels monotonic)
        #pragma unroll
        for (int off = 1; off < 16; off <<= 1) {
          const bool m = (l16 + off < 16) && (slab[cloc + off] == lab);
          float s0 = __shfl(v0, lane + off);
          float s1 = __shfl(v1, lane + off);
          float s2 = __shfl(v2, lane + off);
          float s3 = __shfl(v3, lane + off);
          if (m) { v0 += s0; v1 += s1; v2 += s2; v3 += s3; }
        }
        const bool head = (l16 == 0) || (slab[cloc - 1] != lab);
        if (head) {
          float* po = outp + (size_t)(rstart + rbase) * C_ + lab;
          atomicAdd(po,           v0);
          atomicAdd(po + C_,      v1);
          atomicAdd(po + 2 * C_,  v2);
          atomicAdd(po + 3 * C_,  v3);
        }
      }
    }
  } else {
    #pragma unroll
    for (int mt = 0; mt < 4; ++mt) {
      const int rbase = wm * 64 + mt * 16 + quad * 4;
      #pragma unroll
      for (int nt = 0; nt < 4; ++nt) {
        const int cc = nstart + wn * 64 + nt * 16 + l16;
        const float bv = bias[cc];
        #pragma unroll
        for (int r = 0; r < 4; ++r) {
          float v = acc[mt][nt][r] + bv;
          outp[(size_t)(rstart + rbase + r) * H_ + cc] = v > 0.f ? v : 0.f;
        }
      }
    }
  }
}

// ---------------- gate: g = x @ fc2^T + b; alpha = sigmoid, beta = softplus + 1e-3 --
__global__ void gate_kernel(const float* __restrict__ x, const float* __restrict__ fc2_w,
                            const float* __restrict__ fc2_b, float* __restrict__ ab) {
  const int w = (int)((blockIdx.x * blockDim.x + threadIdx.x) >> 6);
  const int lane = threadIdx.x & 63;
  if (w >= B_) return;
  const float* xr = x + (size_t)w * H_;
  float g0 = 0.f, g1 = 0.f;
  #pragma unroll
  for (int j = 0; j < H_; j += 64) {
    float v = xr[j + lane];
    g0 += v * fc2_w[j + lane];
    g1 += v * fc2_w[H_ + j + lane];
  }
  #pragma unroll
  for (int off = 32; off > 0; off >>= 1) {
    g0 += __shfl_down(g0, off);
    g1 += __shfl_down(g1, off);
  }
  if (lane == 0) {
    g0 += fc2_b[0];
    g1 += fc2_b[1];
    ab[w]      = 1.f / (1.f + __expf(-g0));                                  // alpha
    ab[B_ + w] = fmaxf(g1, 0.f) + log1pf(__expf(-fabsf(g1))) + 0.001f;       // beta
  }
}

// ---------------- fusion: out = ((1-a)*z + a*c) * post_scale (in-place over c) -------
__global__ void fuse_kernel(float* __restrict__ out, const float* __restrict__ z,
                            const float* __restrict__ ps) {
  const int b = blockIdx.x;
  const int t = threadIdx.x;
  if (t >= C_ / 4) return;
  const float a = out[(size_t)B_ * C_ + b];
  const float scale = ps[0];
  float4* o4 = (float4*)(out + (size_t)b * C_);
  const float4* z4 = (const float4*)(z + (size_t)b * C_);
  float4 c = o4[t];
  float4 zz = z4[t];
  float4 r;
  r.x = ((1.f - a) * zz.x + a * c.x) * scale;
  r.y = ((1.f - a) * zz.y + a * c.y) * scale;
  r.z = ((1.f - a) * zz.z + a * c.z) * scale;
  r.w = ((1.f - a) * zz.w + a * c.w) * scale;
  o4[t] = r;
}

extern "C" void kernel_launch(void* const* d_in, const int* in_sizes, int n_in,
                              void* d_out, int out_size, void* d_ws, size_t ws_size,
                              hipStream_t stream) {
  const float* q          = (const float*)d_in[0];
  const float* z          = (const float*)d_in[1];
  const float* keys       = (const float*)d_in[2];
  const float* values     = (const float*)d_in[3];
  const float* fc1_w      = (const float*)d_in[4];
  const float* fc1_b      = (const float*)d_in[5];
  const float* fc2_w      = (const float*)d_in[6];
  const float* fc2_b      = (const float*)d_in[7];
  const float* post_scale = (const float*)d_in[8];
  float* out = (float*)d_out;

  // ws layout (byte offsets)
  char* ws = (char*)d_ws;
  short* qb      = (short*)(ws);                       //  8,388,608
  short* keysb   = (short*)(ws + 8388608);             // 32,768,000
  short* fc1b    = (short*)(ws + 41156608);            //    524,288
  int*   labels  = (int*)  (ws + 41680896);            //     64,000
  float* x       = (float*)(ws + 41744896);            //  4,194,304
  int*   hist    = (int*)  (ws + 45939200);            //      4,096
  int*   cnt     = (int*)  (ws + 45943296);            //      4,096
  int*   boff    = (int*)  (ws + 45947392);            //      4,096
  int*   posmap  = (int*)  (ws + 45951488);            //     64,000
  int*   labsort = (int*)  (ws + 46015488);            //     64,000

  float* alpha = out + (size_t)B_ * C_;   // alpha/beta written directly to output tail
  float* beta  = alpha + B_;

  hipMemsetAsync(out, 0, (size_t)B_ * C_ * sizeof(float), stream);  // c accumulator
  hipMemsetAsync(hist, 0, 8192, stream);                            // hist + cnt

  labels_kernel<<<(NS_ * 64) / 256, 256, 0, stream>>>(values, labels, hist);
  scan_kernel<<<1, 1024, 0, stream>>>(hist, boff);
  scatter_kernel<<<(NS_ + 255) / 256, 256, 0, stream>>>(labels, boff, cnt, posmap, labsort);

  convert_kernel<<<2048, 256, 0, stream>>>(
      (const float4*)q, (const float4*)keys, (const float4*)fc1_w, posmap,
      (ushort4*)qb, (ushort4*)keysb, (ushort4*)fc1b);

  gemm_kernel<1><<<dim3(B_ / 128, H_ / 128), 256, 0, stream>>>(
      qb, fc1b, nullptr, fc1_b, x, nullptr);

  gate_kernel<<<(B_ * 64) / 256, 256, 0, stream>>>(x, fc2_w, fc2_b, alpha);

  gemm_kernel<0><<<dim3(B_ / 128, NS_ / 128), 256, 0, stream>>>(
      qb, keysb, beta, nullptr, out, labsort);

  fuse_kernel<<<B_, 256, 0, stream>>>(out, z, post_scale);
}

// Round 5
// 398.766 us; speedup vs baseline: 1.3557x; 1.3557x over previous
//
#include <hip/hip_runtime.h>
#include <hip/hip_bf16.h>
#include <stdint.h>

#define B_  4096
#define D_  1024
#define NS_ 16000
#define C_  1000
#define H_  256
#define LBLK 4000   // blocks of prep_kernel doing label extraction (4 waves/block)

typedef __attribute__((ext_vector_type(8))) short bf16x8;
typedef __attribute__((ext_vector_type(4))) float f32x4;

__device__ __forceinline__ unsigned short f2bf(float f) {
  union { float f; unsigned u; } v; v.f = f;
  unsigned u = v.u;
  u += 0x7FFF + ((u >> 16) & 1);   // round-to-nearest-even
  return (unsigned short)(u >> 16);
}

__device__ __forceinline__ float bf2f(unsigned short h) {
  union { unsigned u; float f; } v; v.u = ((unsigned)h) << 16;
  return v.f;
}

// ---------------- fused prep: label extraction + fp32->bf16 convert -----------------
// blocks [0, LBLK): wave per support row, find one-hot index (early exit)
// blocks [LBLK, ...): grid-stride convert of q / keys(unpermuted) / fc1
__global__ void prep_kernel(const float4* __restrict__ q, const float4* __restrict__ keys,
                            const float4* __restrict__ fc1, const float* __restrict__ values,
                            ushort4* __restrict__ qb, ushort4* __restrict__ keysb,
                            ushort4* __restrict__ fc1b, int* __restrict__ labels) {
  if (blockIdx.x < LBLK) {
    const int s = blockIdx.x * 4 + (threadIdx.x >> 6);
    const int lane = threadIdx.x & 63;
    const float4* row = (const float4*)(values + (size_t)s * C_);
    int lab = -1;
    for (int j = lane; j < C_ / 4; j += 64) {
      float4 v = row[j];
      if (v.x > 0.5f) lab = j * 4 + 0;
      if (v.y > 0.5f) lab = j * 4 + 1;
      if (v.z > 0.5f) lab = j * 4 + 2;
      if (v.w > 0.5f) lab = j * 4 + 3;
      if (__ballot(lab >= 0)) break;     // one-hot: whole wave exits once found
    }
    if (lab >= 0) labels[s] = lab;
    return;
  }
  const size_t nq = (size_t)B_ * D_ / 4;
  const size_t nk = (size_t)NS_ * D_ / 4;
  const size_t nf = (size_t)H_ * D_ / 4;
  const size_t total = nq + nk + nf;
  const size_t nblk = gridDim.x - LBLK;
  for (size_t i = (blockIdx.x - LBLK) * (size_t)blockDim.x + threadIdx.x; i < total;
       i += nblk * blockDim.x) {
    const float4* s; ushort4* d; size_t o;
    if (i < nq)            { s = q;    d = qb;    o = i; }
    else if (i < nq + nk)  { s = keys; d = keysb; o = i - nq; }
    else                   { s = fc1;  d = fc1b;  o = i - nq - nk; }
    float4 v = s[o];
    ushort4 r; r.x = f2bf(v.x); r.y = f2bf(v.y); r.z = f2bf(v.z); r.w = f2bf(v.w);
    d[o] = r;
  }
}

// ---------------- single-block counting sort: hist + scan + scatter -----------------
// outputs: boff[0..C_] (global), sortidx[pos] = original support row index
__global__ __launch_bounds__(1024) void sortprep_kernel(const int* __restrict__ labels,
                                                        int* __restrict__ boff,
                                                        int* __restrict__ sortidx) {
  __shared__ int s[1024];
  __shared__ int cnt[1024];
  const int t = threadIdx.x;
  int myl[16];
  #pragma unroll
  for (int i = 0; i < 16; ++i) {
    const int idx = t + i * 1024;
    myl[i] = (idx < NS_) ? labels[idx] : -1;
  }
  s[t] = 0; cnt[t] = 0;
  __syncthreads();
  #pragma unroll
  for (int i = 0; i < 16; ++i)
    if (myl[i] >= 0) atomicAdd(&s[myl[i]], 1);
  __syncthreads();
  // in-place inclusive Hillis-Steele scan over s[0..1023]
  for (int off = 1; off < 1024; off <<= 1) {
    int u = (t >= off) ? s[t - off] : 0;
    __syncthreads();
    s[t] += u;
    __syncthreads();
  }
  if (t == 0) boff[0] = 0;
  if (t < C_) boff[t + 1] = s[t];
  __syncthreads();
  #pragma unroll
  for (int i = 0; i < 16; ++i) {
    const int lab = myl[i];
    if (lab >= 0) {
      const int base = lab ? s[lab - 1] : 0;           // exclusive offset
      const int pos = base + atomicAdd(&cnt[lab], 1);
      sortidx[pos] = t + i * 1024;
    }
  }
}

// ---------------- 128x128 bf16 MFMA GEMM (A [M,K], B [N,K], both row-major) ---------
// MODE 0: B rows gathered via sortidx; epilogue -> affbuf[row*affStride + col] =
//         bf16(exp(beta[row]*acc))
// MODE 1: x epilogue -> outp[row*H_ + col] = relu(acc + bias[col])
// LDS k-chunk XOR swizzle: LDS[r][c] holds global 16B k-chunk (c ^ (r&7)).
template<int MODE>
__global__ __launch_bounds__(256, 2) void gemm_kernel(
    const short* __restrict__ A, const short* __restrict__ Bm,
    const float* __restrict__ beta, const float* __restrict__ bias,
    float* __restrict__ outp, unsigned short* __restrict__ affbuf, long affStride,
    const int* __restrict__ sortidx)
{
  __shared__ short As[128 * 64];
  __shared__ short Bs[128 * 64];
  __shared__ float sbeta[128];

  const int tid  = threadIdx.x;
  const int wave = tid >> 6, lane = tid & 63;
  const int quad = lane >> 4, l16 = lane & 15;
  const int wm = wave >> 1, wn = wave & 1;     // 2x2 wave grid, 64x64 per wave
  const int rstart = blockIdx.x * 128;
  const int nstart = blockIdx.y * 128;

  if (MODE == 0 && tid < 128) sbeta[tid] = beta[rstart + tid];

  const int r_  = (lane >> 3);             // 0..7 (row within 8-row chunk)
  const int kc_ = ((lane & 7) ^ r_) * 8;   // swizzled 16B k-chunk element offset

  // B-tile source rows (gathered through the counting sort for MODE 0)
  int brow[4];
  #pragma unroll
  for (int i = 0; i < 4; ++i) {
    const int r = (i * 4 + wave) * 8 + r_;
    brow[i] = (MODE == 0) ? sortidx[nstart + r] : (nstart + r);
  }

  f32x4 acc[4][4];
  #pragma unroll
  for (int i = 0; i < 4; ++i)
    #pragma unroll
    for (int j = 0; j < 4; ++j) acc[i][j] = (f32x4)0.f;

  for (int kt = 0; kt < D_; kt += 64) {
    __syncthreads();
    #pragma unroll
    for (int i = 0; i < 4; ++i) {
      const int chunk = i * 4 + wave;       // 0..15, wave-uniform
      const int r = chunk * 8 + r_;         // 0..127
      const short* gA = A  + (size_t)(rstart + r) * D_ + kt + kc_;
      const short* gB = Bm + (size_t)brow[i] * D_ + kt + kc_;
      __builtin_amdgcn_global_load_lds(
          (const __attribute__((address_space(1))) void*)gA,
          (__attribute__((address_space(3))) void*)(As + chunk * 512), 16, 0, 0);
      __builtin_amdgcn_global_load_lds(
          (const __attribute__((address_space(1))) void*)gB,
          (__attribute__((address_space(3))) void*)(Bs + chunk * 512), 16, 0, 0);
    }
    __syncthreads();
    #pragma unroll
    for (int ks = 0; ks < 64; ks += 32) {
      bf16x8 af[4], bfr[4];
      const int kb = (ks >> 3) + quad;      // global k-chunk index 0..7
      #pragma unroll
      for (int mt = 0; mt < 4; ++mt) {
        const int row = wm * 64 + mt * 16 + l16;
        af[mt] = *(const bf16x8*)(As + row * 64 + ((kb ^ (row & 7)) << 3));
      }
      #pragma unroll
      for (int nt = 0; nt < 4; ++nt) {
        const int row = wn * 64 + nt * 16 + l16;
        bfr[nt] = *(const bf16x8*)(Bs + row * 64 + ((kb ^ (row & 7)) << 3));
      }
      #pragma unroll
      for (int mt = 0; mt < 4; ++mt)
        #pragma unroll
        for (int nt = 0; nt < 4; ++nt)
          acc[mt][nt] = __builtin_amdgcn_mfma_f32_16x16x32_bf16(af[mt], bfr[nt], acc[mt][nt], 0, 0, 0);
    }
  }

  if (MODE == 0) {
    #pragma unroll
    for (int mt = 0; mt < 4; ++mt) {
      const int rbase = wm * 64 + mt * 16 + quad * 4;
      #pragma unroll
      for (int nt = 0; nt < 4; ++nt) {
        const long col = nstart + wn * 64 + nt * 16 + l16;
        #pragma unroll
        for (int r = 0; r < 4; ++r) {
          const int row = rbase + r;
          const float v = __expf(sbeta[row] * acc[mt][nt][r]);
          affbuf[(size_t)(rstart + row) * affStride + col] = f2bf(v);
        }
      }
    }
  } else {
    #pragma unroll
    for (int mt = 0; mt < 4; ++mt) {
      const int rbase = wm * 64 + mt * 16 + quad * 4;
      #pragma unroll
      for (int nt = 0; nt < 4; ++nt) {
        const int cc = nstart + wn * 64 + nt * 16 + l16;
        const float bv = bias[cc];
        #pragma unroll
        for (int r = 0; r < 4; ++r) {
          float v = acc[mt][nt][r] + bv;
          outp[(size_t)(rstart + rbase + r) * H_ + cc] = v > 0.f ? v : 0.f;
        }
      }
    }
  }
}

// ---------------- gate: g = x @ fc2^T + b; alpha = sigmoid, beta = softplus + 1e-3 --
__global__ void gate_kernel(const float* __restrict__ x, const float* __restrict__ fc2_w,
                            const float* __restrict__ fc2_b, float* __restrict__ ab) {
  const int w = (int)((blockIdx.x * blockDim.x + threadIdx.x) >> 6);
  const int lane = threadIdx.x & 63;
  if (w >= B_) return;
  const float* xr = x + (size_t)w * H_;
  float g0 = 0.f, g1 = 0.f;
  #pragma unroll
  for (int j = 0; j < H_; j += 64) {
    float v = xr[j + lane];
    g0 += v * fc2_w[j + lane];
    g1 += v * fc2_w[H_ + j + lane];
  }
  #pragma unroll
  for (int off = 32; off > 0; off >>= 1) {
    g0 += __shfl_down(g0, off);
    g1 += __shfl_down(g1, off);
  }
  if (lane == 0) {
    g0 += fc2_b[0];
    g1 += fc2_b[1];
    ab[w]      = 1.f / (1.f + __expf(-g0));                                  // alpha
    ab[B_ + w] = fmaxf(g1, 0.f) + log1pf(__expf(-fabsf(g1))) + 0.001f;       // beta
  }
}

// ---------------- segmented sum over label buckets, LDS-staged ----------------------
// flags bit0 = first chunk (write, don't read out); bit1 = final chunk (apply fusion)
__global__ __launch_bounds__(256) void segsum_kernel(
    const unsigned short* __restrict__ aff, const int* __restrict__ boff,
    float* __restrict__ out, const float* __restrict__ z, const float* __restrict__ ps,
    int n0, int n1, long affStride, int flags) {
  __shared__ unsigned short srow[16384];
  __shared__ int sboff[C_ + 1];
  const int b = blockIdx.x;
  const int t = threadIdx.x;
  const int nc = n1 - n0;                      // multiple of 128
  const int4* src = (const int4*)(aff + (size_t)b * affStride);
  int4* dst = (int4*)srow;
  for (int i = t; i < nc / 8; i += 256) dst[i] = src[i];
  for (int i = t; i <= C_; i += 256) sboff[i] = boff[i];
  __syncthreads();
  float a = 0.f, sc = 1.f;
  if (flags & 2) { a = out[(size_t)B_ * C_ + b]; sc = ps[0]; }
  for (int lab = t; lab < C_; lab += 256) {
    int s0 = sboff[lab], s1 = sboff[lab + 1];
    if (s0 < n0) s0 = n0;
    if (s1 > n1) s1 = n1;
    float sum = 0.f;
    for (int s = s0; s < s1; ++s) sum += bf2f(srow[s - n0]);
    const size_t oi = (size_t)b * C_ + lab;
    float c = (flags & 1) ? sum : out[oi] + sum;
    out[oi] = (flags & 2) ? ((1.f - a) * z[oi] + a * c) * sc : c;
  }
}

extern "C" void kernel_launch(void* const* d_in, const int* in_sizes, int n_in,
                              void* d_out, int out_size, void* d_ws, size_t ws_size,
                              hipStream_t stream) {
  const float* q          = (const float*)d_in[0];
  const float* z          = (const float*)d_in[1];
  const float* keys       = (const float*)d_in[2];
  const float* values     = (const float*)d_in[3];
  const float* fc1_w      = (const float*)d_in[4];
  const float* fc1_b      = (const float*)d_in[5];
  const float* fc2_w      = (const float*)d_in[6];
  const float* fc2_b      = (const float*)d_in[7];
  const float* post_scale = (const float*)d_in[8];
  float* out = (float*)d_out;

  // ws layout (byte offsets)
  char* ws = (char*)d_ws;
  short*          qb      = (short*)(ws);                       //  8,388,608
  short*          keysb   = (short*)(ws + 8388608);             // 32,768,000
  short*          fc1b    = (short*)(ws + 41156608);            //    524,288
  int*            labels  = (int*)  (ws + 41680896);            //     64,000
  float*          x       = (float*)(ws + 41744896);            //  4,194,304
  int*            boff    = (int*)  (ws + 45939200);            //      4,096
  int*            sortidx = (int*)  (ws + 45943296);            //     64,000
  unsigned short* aff     = (unsigned short*)(ws + 46007296);   //  remainder

  float* alpha = out + (size_t)B_ * C_;   // alpha/beta written directly to output tail
  float* beta  = alpha + B_;

  // aff chunking by available workspace (deterministic per call)
  long avail = (long)ws_size - 46007296L;
  long maxN = (avail / (B_ * 2)) & ~127L;       // columns per chunk, multiple of 128
  if (maxN > NS_) maxN = NS_;
  if (maxN > 16384) maxN = 16384;               // segsum LDS staging capacity
  if (maxN < 128) maxN = 128;

  prep_kernel<<<LBLK + 2048, 256, 0, stream>>>(
      (const float4*)q, (const float4*)keys, (const float4*)fc1_w, values,
      (ushort4*)qb, (ushort4*)keysb, (ushort4*)fc1b, labels);

  sortprep_kernel<<<1, 1024, 0, stream>>>(labels, boff, sortidx);

  gemm_kernel<1><<<dim3(B_ / 128, H_ / 128), 256, 0, stream>>>(
      qb, fc1b, nullptr, fc1_b, x, nullptr, 0, nullptr);

  gate_kernel<<<(B_ * 64) / 256, 256, 0, stream>>>(x, fc2_w, fc2_b, alpha);

  for (long n0 = 0; n0 < NS_; n0 += maxN) {
    long nc = NS_ - n0; if (nc > maxN) nc = maxN;
    gemm_kernel<0><<<dim3(B_ / 128, (int)(nc / 128)), 256, 0, stream>>>(
        qb, keysb, beta, nullptr, nullptr, aff, maxN, sortidx + n0);
    int flags = (n0 == 0 ? 1 : 0) | ((n0 + nc >= NS_) ? 2 : 0);
    segsum_kernel<<<B_, 256, 0, stream>>>(aff, boff, out, z, post_scale,
                                          (int)n0, (int)(n0 + nc), maxN, flags);
  }
}

// Round 6
// 344.922 us; speedup vs baseline: 1.5674x; 1.1561x over previous
//
#include <hip/hip_runtime.h>
#include <hip/hip_bf16.h>
#include <stdint.h>

#define B_  4096
#define D_  1024
#define NS_ 16000
#define C_  1000
#define H_  256
#define LBLK 4000   // blocks of prep_kernel doing label extraction (4 waves/block)

typedef __attribute__((ext_vector_type(8))) short bf16x8;
typedef __attribute__((ext_vector_type(4))) float f32x4;
typedef __attribute__((ext_vector_type(16))) float f32x16;
typedef __attribute__((ext_vector_type(8))) int i32x8;

__device__ __forceinline__ unsigned short f2bf(float f) {
  union { float f; unsigned u; } v; v.f = f;
  unsigned u = v.u;
  u += 0x7FFF + ((u >> 16) & 1);   // round-to-nearest-even
  return (unsigned short)(u >> 16);
}

__device__ __forceinline__ float bf2f(unsigned short h) {
  union { unsigned u; float f; } v; v.u = ((unsigned)h) << 16;
  return v.f;
}

// ---------------- fused prep: labels+hist, and fp32 -> bf16/fp8 conversion ----------
// blocks [0, LBLK): wave per support row -> labels[] + global hist atomics
// blocks [LBLK, ...): grid-stride: q -> qb(bf16) + q8(fp8 x64); keys -> keys8(fp8 x64);
//                     fc1 -> fc1b(bf16)
__global__ void prep_kernel(const float4* __restrict__ q, const float4* __restrict__ keys,
                            const float4* __restrict__ fc1, const float* __restrict__ values,
                            ushort4* __restrict__ qb, int* __restrict__ q8,
                            int* __restrict__ keys8, ushort4* __restrict__ fc1b,
                            int* __restrict__ labels, int* __restrict__ hist) {
  if (blockIdx.x < LBLK) {
    const int s = blockIdx.x * 4 + (threadIdx.x >> 6);
    const int lane = threadIdx.x & 63;
    const float4* row = (const float4*)(values + (size_t)s * C_);
    int lab = -1;
    for (int j = lane; j < C_ / 4; j += 64) {
      float4 v = row[j];
      if (v.x > 0.5f) lab = j * 4 + 0;
      if (v.y > 0.5f) lab = j * 4 + 1;
      if (v.z > 0.5f) lab = j * 4 + 2;
      if (v.w > 0.5f) lab = j * 4 + 3;
      if (__ballot(lab >= 0)) break;     // one-hot: whole wave exits once found
    }
    if (lab >= 0) { labels[s] = lab; atomicAdd(&hist[lab], 1); }
    return;
  }
  const size_t nq = (size_t)B_ * D_ / 4;
  const size_t nk = (size_t)NS_ * D_ / 4;
  const size_t nf = (size_t)H_ * D_ / 4;
  const size_t total = nq + nk + nf;
  const size_t nblk = gridDim.x - LBLK;
  for (size_t i = (blockIdx.x - LBLK) * (size_t)blockDim.x + threadIdx.x; i < total;
       i += nblk * blockDim.x) {
    if (i < nq) {
      float4 v = q[i];
      ushort4 r; r.x = f2bf(v.x); r.y = f2bf(v.y); r.z = f2bf(v.z); r.w = f2bf(v.w);
      qb[i] = r;
      int p = __builtin_amdgcn_cvt_pk_fp8_f32(v.x * 64.f, v.y * 64.f, 0, false);
      p     = __builtin_amdgcn_cvt_pk_fp8_f32(v.z * 64.f, v.w * 64.f, p, true);
      q8[i] = p;
    } else if (i < nq + nk) {
      size_t o = i - nq;
      float4 v = keys[o];
      int p = __builtin_amdgcn_cvt_pk_fp8_f32(v.x * 64.f, v.y * 64.f, 0, false);
      p     = __builtin_amdgcn_cvt_pk_fp8_f32(v.z * 64.f, v.w * 64.f, p, true);
      keys8[o] = p;
    } else {
      size_t o = i - nq - nk;
      float4 v = fc1[o];
      ushort4 r; r.x = f2bf(v.x); r.y = f2bf(v.y); r.z = f2bf(v.z); r.w = f2bf(v.w);
      fc1b[o] = r;
    }
  }
}

// ---------------- exclusive prefix scan of hist -> boff[0..C_] (single block) -------
__global__ void scan_kernel(const int* __restrict__ hist, int* __restrict__ boff) {
  __shared__ int s[1024];
  const int t = threadIdx.x;
  int v = (t < C_) ? hist[t] : 0;
  s[t] = v; __syncthreads();
  for (int off = 1; off < 1024; off <<= 1) {
    int u = (t >= off) ? s[t - off] : 0;
    __syncthreads();
    s[t] += u;
    __syncthreads();
  }
  if (t == 0) boff[0] = 0;
  if (t < C_) boff[t + 1] = s[t];
}

// ---------------- scatter: sortidx[pos] = original support row --------------------
__global__ void scatter_kernel(const int* __restrict__ labels, const int* __restrict__ boff,
                               int* __restrict__ cnt, int* __restrict__ sortidx) {
  const int sidx = blockIdx.x * blockDim.x + threadIdx.x;
  if (sidx >= NS_) return;
  const int lab = labels[sidx];
  const int pos = boff[lab] + atomicAdd(&cnt[lab], 1);
  sortidx[pos] = sidx;
}

// ---------------- bf16 128x128 MFMA GEMM (MODE 1 only: x = relu(A@B^T + bias)) ------
template<int MODE>
__global__ __launch_bounds__(256, 2) void gemm_kernel(
    const short* __restrict__ A, const short* __restrict__ Bm,
    const float* __restrict__ bias, float* __restrict__ outp)
{
  __shared__ short As[128 * 64];
  __shared__ short Bs[128 * 64];

  const int tid  = threadIdx.x;
  const int wave = tid >> 6, lane = tid & 63;
  const int quad = lane >> 4, l16 = lane & 15;
  const int wm = wave >> 1, wn = wave & 1;     // 2x2 wave grid, 64x64 per wave
  const int rstart = blockIdx.x * 128;
  const int nstart = blockIdx.y * 128;

  f32x4 acc[4][4];
  #pragma unroll
  for (int i = 0; i < 4; ++i)
    #pragma unroll
    for (int j = 0; j < 4; ++j) acc[i][j] = (f32x4)0.f;

  const int r_  = (lane >> 3);             // 0..7 (row within 8-row chunk)
  const int kc_ = ((lane & 7) ^ r_) * 8;   // swizzled 16B k-chunk element offset

  for (int kt = 0; kt < D_; kt += 64) {
    __syncthreads();
    #pragma unroll
    for (int i = 0; i < 4; ++i) {
      const int chunk = i * 4 + wave;       // 0..15, wave-uniform
      const int r = chunk * 8 + r_;         // 0..127
      const short* gA = A  + (size_t)(rstart + r) * D_ + kt + kc_;
      const short* gB = Bm + (size_t)(nstart + r) * D_ + kt + kc_;
      __builtin_amdgcn_global_load_lds(
          (const __attribute__((address_space(1))) void*)gA,
          (__attribute__((address_space(3))) void*)(As + chunk * 512), 16, 0, 0);
      __builtin_amdgcn_global_load_lds(
          (const __attribute__((address_space(1))) void*)gB,
          (__attribute__((address_space(3))) void*)(Bs + chunk * 512), 16, 0, 0);
    }
    __syncthreads();
    #pragma unroll
    for (int ks = 0; ks < 64; ks += 32) {
      bf16x8 af[4], bfr[4];
      const int kb = (ks >> 3) + quad;      // global k-chunk index 0..7
      #pragma unroll
      for (int mt = 0; mt < 4; ++mt) {
        const int row = wm * 64 + mt * 16 + l16;
        af[mt] = *(const bf16x8*)(As + row * 64 + ((kb ^ (row & 7)) << 3));
      }
      #pragma unroll
      for (int nt = 0; nt < 4; ++nt) {
        const int row = wn * 64 + nt * 16 + l16;
        bfr[nt] = *(const bf16x8*)(Bs + row * 64 + ((kb ^ (row & 7)) << 3));
      }
      #pragma unroll
      for (int mt = 0; mt < 4; ++mt)
        #pragma unroll
        for (int nt = 0; nt < 4; ++nt)
          acc[mt][nt] = __builtin_amdgcn_mfma_f32_16x16x32_bf16(af[mt], bfr[nt], acc[mt][nt], 0, 0, 0);
    }
  }

  #pragma unroll
  for (int mt = 0; mt < 4; ++mt) {
    const int rbase = wm * 64 + mt * 16 + quad * 4;
    #pragma unroll
    for (int nt = 0; nt < 4; ++nt) {
      const int cc = nstart + wn * 64 + nt * 16 + l16;
      const float bv = bias[cc];
      #pragma unroll
      for (int r = 0; r < 4; ++r) {
        float v = acc[mt][nt][r] + bv;
        outp[(size_t)(rstart + rbase + r) * H_ + cc] = v > 0.f ? v : 0.f;
      }
    }
  }
}

// ---------------- MX-fp8 128x128 GEMM (sim) with exp epilogue -----------------------
// A8 [B_][1024B] fp8(x64), B8 [NS_][1024B] fp8(x64), rows of B gathered via sortidx.
// mfma_scale_f32_32x32x64_f8f6f4 with e8m0 scale 121 (=2^-6) per operand undoes x64^2.
// LDS: 16B k-chunk XOR swizzle (chunk c of row r stored at c ^ (r&7)).
__device__ __forceinline__ i32x8 mx_frag(const char* base, int lrow, int kh, int sel) {
  const int c0 = kh * 4 + sel * 2;
  const int s = lrow & 7;
  const int4 lo = *(const int4*)(base + lrow * 128 + (((c0    ) ^ s) << 4));
  const int4 hi = *(const int4*)(base + lrow * 128 + (((c0 + 1) ^ s) << 4));
  i32x8 f;
  f[0] = lo.x; f[1] = lo.y; f[2] = lo.z; f[3] = lo.w;
  f[4] = hi.x; f[5] = hi.y; f[6] = hi.z; f[7] = hi.w;
  return f;
}

__global__ __launch_bounds__(256, 2) void mxgemm_kernel(
    const char* __restrict__ A8, const char* __restrict__ B8,
    const float* __restrict__ beta, unsigned short* __restrict__ affbuf,
    long affStride, const int* __restrict__ sortidx)
{
  __shared__ char As[128 * 128];
  __shared__ char Bs[128 * 128];
  __shared__ float sbeta[128];

  const int tid  = threadIdx.x;
  const int wave = tid >> 6, lane = tid & 63;
  const int sel  = lane >> 5, l32 = lane & 31;
  const int wm = wave >> 1, wn = wave & 1;     // 2x2 wave grid, 64x64 per wave
  const int rstart = blockIdx.x * 128;
  const int nstart = blockIdx.y * 128;

  if (tid < 128) sbeta[tid] = beta[rstart + tid];

  // staging geometry: slot s = wave*256 + i*64 + lane; row = s>>3, chunk c = s&7
  const int srow_ = (lane >> 3);           // row offset within 8-row group
  const int gch_  = (lane & 7) ^ srow_;    // swizzled source chunk (since row&7 == lane>>3)

  int arow[4], brow[4];
  #pragma unroll
  for (int i = 0; i < 4; ++i) {
    const int row = wave * 32 + i * 8 + srow_;
    arow[i] = rstart + row;
    brow[i] = sortidx[nstart + row];
  }

  f32x16 acc[2][2];
  #pragma unroll
  for (int i = 0; i < 2; ++i)
    #pragma unroll
    for (int j = 0; j < 2; ++j) acc[i][j] = (f32x16)0.f;

  for (int kt = 0; kt < D_; kt += 128) {
    __syncthreads();
    #pragma unroll
    for (int i = 0; i < 4; ++i) {
      const char* gA = A8 + (size_t)arow[i] * D_ + kt + (gch_ << 4);
      const char* gB = B8 + (size_t)brow[i] * D_ + kt + (gch_ << 4);
      __builtin_amdgcn_global_load_lds(
          (const __attribute__((address_space(1))) void*)gA,
          (__attribute__((address_space(3))) void*)(As + wave * 4096 + i * 1024), 16, 0, 0);
      __builtin_amdgcn_global_load_lds(
          (const __attribute__((address_space(1))) void*)gB,
          (__attribute__((address_space(3))) void*)(Bs + wave * 4096 + i * 1024), 16, 0, 0);
    }
    __syncthreads();
    #pragma unroll
    for (int kh = 0; kh < 2; ++kh) {
      i32x8 a0 = mx_frag(As, wm * 64 +  0 + l32, kh, sel);
      i32x8 a1 = mx_frag(As, wm * 64 + 32 + l32, kh, sel);
      i32x8 b0 = mx_frag(Bs, wn * 64 +  0 + l32, kh, sel);
      i32x8 b1 = mx_frag(Bs, wn * 64 + 32 + l32, kh, sel);
      acc[0][0] = __builtin_amdgcn_mfma_scale_f32_32x32x64_f8f6f4(a0, b0, acc[0][0], 0, 0, 0, 121, 0, 121);
      acc[0][1] = __builtin_amdgcn_mfma_scale_f32_32x32x64_f8f6f4(a0, b1, acc[0][1], 0, 0, 0, 121, 0, 121);
      acc[1][0] = __builtin_amdgcn_mfma_scale_f32_32x32x64_f8f6f4(a1, b0, acc[1][0], 0, 0, 0, 121, 0, 121);
      acc[1][1] = __builtin_amdgcn_mfma_scale_f32_32x32x64_f8f6f4(a1, b1, acc[1][1], 0, 0, 0, 121, 0, 121);
    }
  }

  // C/D 32x32 layout: col = lane&31, row = (reg&3) + 8*(reg>>2) + 4*(lane>>5)
  #pragma unroll
  for (int mt = 0; mt < 2; ++mt) {
    #pragma unroll
    for (int nt = 0; nt < 2; ++nt) {
      const long col = nstart + wn * 64 + nt * 32 + l32;
      #pragma unroll
      for (int r = 0; r < 16; ++r) {
        const int row = wm * 64 + mt * 32 + (r & 3) + 8 * (r >> 2) + 4 * sel;
        const float v = __expf(sbeta[row] * acc[mt][nt][r]);
        affbuf[(size_t)(rstart + row) * affStride + col] = f2bf(v);
      }
    }
  }
}

// ---------------- gate: g = x @ fc2^T + b; alpha = sigmoid, beta = softplus + 1e-3 --
__global__ void gate_kernel(const float* __restrict__ x, const float* __restrict__ fc2_w,
                            const float* __restrict__ fc2_b, float* __restrict__ ab) {
  const int w = (int)((blockIdx.x * blockDim.x + threadIdx.x) >> 6);
  const int lane = threadIdx.x & 63;
  if (w >= B_) return;
  const float* xr = x + (size_t)w * H_;
  float g0 = 0.f, g1 = 0.f;
  #pragma unroll
  for (int j = 0; j < H_; j += 64) {
    float v = xr[j + lane];
    g0 += v * fc2_w[j + lane];
    g1 += v * fc2_w[H_ + j + lane];
  }
  #pragma unroll
  for (int off = 32; off > 0; off >>= 1) {
    g0 += __shfl_down(g0, off);
    g1 += __shfl_down(g1, off);
  }
  if (lane == 0) {
    g0 += fc2_b[0];
    g1 += fc2_b[1];
    ab[w]      = 1.f / (1.f + __expf(-g0));                                  // alpha
    ab[B_ + w] = fmaxf(g1, 0.f) + log1pf(__expf(-fabsf(g1))) + 0.001f;       // beta
  }
}

// ---------------- segmented sum over label buckets, LDS-staged ----------------------
// flags bit0 = first chunk (write, don't read out); bit1 = final chunk (apply fusion)
__global__ __launch_bounds__(256) void segsum_kernel(
    const unsigned short* __restrict__ aff, const int* __restrict__ boff,
    float* __restrict__ out, const float* __restrict__ z, const float* __restrict__ ps,
    int n0, int n1, long affStride, int flags) {
  __shared__ unsigned short srow[16384];
  __shared__ int sboff[C_ + 1];
  const int b = blockIdx.x;
  const int t = threadIdx.x;
  const int nc = n1 - n0;                      // multiple of 128
  const int4* src = (const int4*)(aff + (size_t)b * affStride);
  int4* dst = (int4*)srow;
  for (int i = t; i < nc / 8; i += 256) dst[i] = src[i];
  for (int i = t; i <= C_; i += 256) sboff[i] = boff[i];
  __syncthreads();
  float a = 0.f, sc = 1.f;
  if (flags & 2) { a = out[(size_t)B_ * C_ + b]; sc = ps[0]; }
  for (int lab = t; lab < C_; lab += 256) {
    int s0 = sboff[lab], s1 = sboff[lab + 1];
    if (s0 < n0) s0 = n0;
    if (s1 > n1) s1 = n1;
    float sum = 0.f;
    for (int s = s0; s < s1; ++s) sum += bf2f(srow[s - n0]);
    const size_t oi = (size_t)b * C_ + lab;
    float c = (flags & 1) ? sum : out[oi] + sum;
    out[oi] = (flags & 2) ? ((1.f - a) * z[oi] + a * c) * sc : c;
  }
}

extern "C" void kernel_launch(void* const* d_in, const int* in_sizes, int n_in,
                              void* d_out, int out_size, void* d_ws, size_t ws_size,
                              hipStream_t stream) {
  const float* q          = (const float*)d_in[0];
  const float* z          = (const float*)d_in[1];
  const float* keys       = (const float*)d_in[2];
  const float* values     = (const float*)d_in[3];
  const float* fc1_w      = (const float*)d_in[4];
  const float* fc1_b      = (const float*)d_in[5];
  const float* fc2_w      = (const float*)d_in[6];
  const float* fc2_b      = (const float*)d_in[7];
  const float* post_scale = (const float*)d_in[8];
  float* out = (float*)d_out;

  // ws layout (byte offsets)
  char* ws = (char*)d_ws;
  short*          qb      = (short*)(ws);                       //  8,388,608
  char*           q8      = (char*) (ws +  8388608);            //  4,194,304
  char*           keys8   = (char*) (ws + 12582912);            // 16,384,000
  short*          fc1b    = (short*)(ws + 28966912);            //    524,288
  int*            labels  = (int*)  (ws + 29491200);            //     64,000
  float*          x       = (float*)(ws + 29555200);            //  4,194,304
  int*            hist    = (int*)  (ws + 33749504);            //      4,096
  int*            cnt     = (int*)  (ws + 33753600);            //      4,096
  int*            boff    = (int*)  (ws + 33757696);            //      4,096
  int*            sortidx = (int*)  (ws + 33761792);            //     64,000
  unsigned short* aff     = (unsigned short*)(ws + 33825792);   //  remainder

  float* alpha = out + (size_t)B_ * C_;   // alpha/beta written directly to output tail
  float* beta  = alpha + B_;

  // aff chunking by available workspace (deterministic per call)
  long avail = (long)ws_size - 33825792L;
  long maxN = (avail / (B_ * 2)) & ~127L;       // columns per chunk, multiple of 128
  if (maxN > NS_) maxN = NS_;
  if (maxN > 16384) maxN = 16384;               // segsum LDS staging capacity
  if (maxN < 128) maxN = 128;

  hipMemsetAsync(hist, 0, 8192, stream);        // hist + cnt

  prep_kernel<<<LBLK + 2048, 256, 0, stream>>>(
      (const float4*)q, (const float4*)keys, (const float4*)fc1_w, values,
      (ushort4*)qb, (int*)q8, (int*)keys8, (ushort4*)fc1b, labels, hist);

  scan_kernel<<<1, 1024, 0, stream>>>(hist, boff);
  scatter_kernel<<<(NS_ + 255) / 256, 256, 0, stream>>>(labels, boff, cnt, sortidx);

  gemm_kernel<1><<<dim3(B_ / 128, H_ / 128), 256, 0, stream>>>(qb, fc1b, fc1_b, x);

  gate_kernel<<<(B_ * 64) / 256, 256, 0, stream>>>(x, fc2_w, fc2_b, alpha);

  for (long n0 = 0; n0 < NS_; n0 += maxN) {
    long nc = NS_ - n0; if (nc > maxN) nc = maxN;
    mxgemm_kernel<<<dim3(B_ / 128, (int)(nc / 128)), 256, 0, stream>>>(
        q8, keys8, beta, aff, maxN, sortidx + n0);
    int flags = (n0 == 0 ? 1 : 0) | ((n0 + nc >= NS_) ? 2 : 0);
    segsum_kernel<<<B_, 256, 0, stream>>>(aff, boff, out, z, post_scale,
                                          (int)n0, (int)(n0 + nc), maxN, flags);
  }
}